// Round 1
// baseline (868.946 us; speedup 1.0000x reference)
//
#include <hip/hip_runtime.h>

// ---------------------------------------------------------------------------
// HierarchicalSparseLayer: top-2 MoE with block-sparse (64x64) masked weights
// B=8192 tokens, D=1024, H=4096, E=16 experts, K=2, + block-sparse cross proj.
// Strategy: gather tokens per expert (exact: routing weight is 0 elsewhere),
// skip zero 64x64 weight blocks, bf16 MFMA with f32 accumulate.
// ---------------------------------------------------------------------------

#define NTOK 8192
#define DIM  1024
#define HID  4096
#define NEXP 16
#define BM   256
#define ROWS_CAP (NTOK*2 + NEXP*BM)   // 20480 (pair rows, expert regions padded to BM)

typedef __attribute__((ext_vector_type(4))) float fx4;
typedef __attribute__((ext_vector_type(4))) unsigned int ux4;
typedef __attribute__((ext_vector_type(2))) unsigned int ux2;
typedef __attribute__((ext_vector_type(8))) short s8v;
union V16 { ux4 u; s8v s; };

__device__ __forceinline__ unsigned int f2bf(float f) {
  unsigned int u = __float_as_uint(f);
  return (u + 0x7fffu + ((u >> 16) & 1u)) >> 16;   // RNE, inputs finite
}

// Mask dtype is detected at runtime: flag 0=u8, 1=i32, 2=f32
__device__ __forceinline__ bool mask_at(const void* m, int flag, size_t idx) {
  if (flag == 0) return ((const unsigned char*)m)[idx] != 0;
  if (flag == 1) return ((const int*)m)[idx] != 0;
  return ((const float*)m)[idx] != 0.0f;
}

// --------------------------- mask dtype detection ---------------------------
// Sample mask1 as u32: 0x3f800000 => f32 evidence (bit1); any other value >1
// => u8 evidence (bit0, e.g. 0x01010101 from byte runs); else (all 0/1) i32.
__global__ void k_detect(const unsigned int* __restrict__ m, int* __restrict__ meta) {
  int bits = 0;
  size_t base = (size_t)blockIdx.x * 4096 + threadIdx.x;
  for (int j = 0; j < 16; j++) {
    unsigned int v = m[base + 256 * j];
    if (v == 0x3f800000u) bits |= 2;
    else if (v > 1u)      bits |= 1;
  }
  if (bits) atomicOr(&meta[1], bits);
}

// --------------------------- routing ---------------------------------------
// meta layout (ints): [0]=flag [1]=detect bits [8..23]=counts [32..48]=offsets
//                     [64..79]=slot counters
__global__ void k_route(const float* __restrict__ x,
                        const float* __restrict__ gw,    // gate_w[-1] [16,1024]
                        const float* __restrict__ temp,  // &temperature[-1]
                        int* __restrict__ top2i, float* __restrict__ top2w,
                        int* __restrict__ meta)
{
  const int t = blockIdx.x;
  const int l = threadIdx.x;   // 64 threads = 1 wave
  const float* xr = x + (size_t)t * DIM;
  float xv[16];
  #pragma unroll
  for (int j = 0; j < 16; j++) xv[j] = xr[l + 64 * j];
  float logit[16];
  #pragma unroll
  for (int e = 0; e < 16; e++) {
    const float* g = gw + (size_t)e * DIM;
    float s = 0.f;
    #pragma unroll
    for (int j = 0; j < 16; j++) s += xv[j] * g[l + 64 * j];
    #pragma unroll
    for (int o = 32; o >= 1; o >>= 1) s += __shfl_xor(s, o);
    logit[e] = s;
  }
  if (l == 0) {
    const float tinv = 1.0f / temp[0];
    int i0 = 0; float v0 = logit[0] * tinv;
    #pragma unroll
    for (int e = 1; e < 16; e++) { float v = logit[e] * tinv; if (v > v0) { v0 = v; i0 = e; } }
    int i1 = -1; float v1 = 0.f; bool first = true;
    #pragma unroll
    for (int e = 0; e < 16; e++) {
      if (e == i0) continue;
      float v = logit[e] * tinv;
      if (first || v > v1) { v1 = v; i1 = e; first = false; }
    }
    float ex = expf(v1 - v0);
    float den = 1.0f + ex;
    top2i[2 * t] = i0; top2i[2 * t + 1] = i1;
    top2w[2 * t] = 1.0f / den; top2w[2 * t + 1] = ex / den;
    atomicAdd(&meta[8 + i0], 1);
    atomicAdd(&meta[8 + i1], 1);
  }
}

__global__ void k_offsets(int* __restrict__ meta) {
  if (threadIdx.x == 0 && blockIdx.x == 0) {
    int o = 0;
    for (int e = 0; e < 16; e++) { meta[32 + e] = o; o += (meta[8 + e] + BM - 1) & ~(BM - 1); }
    meta[48] = o;   // total used rows (multiple of BM)
    int ev = meta[1];
    meta[0] = (ev & 2) ? 2 : ((ev & 1) ? 0 : 1);
  }
}

__global__ void k_assign(const int* __restrict__ top2i, const float* __restrict__ top2w,
                         int* __restrict__ meta, int* __restrict__ tok_of_row,
                         float* __restrict__ row_w)
{
  int t = blockIdx.x * 256 + threadIdx.x;
  if (t >= NTOK) return;
  #pragma unroll
  for (int k = 0; k < 2; k++) {
    int e = top2i[2 * t + k];
    int slot = atomicAdd(&meta[64 + e], 1);
    int row = meta[32 + e] + slot;
    tok_of_row[row] = t;
    row_w[row] = top2w[2 * t + k];
  }
}

__global__ void k_xcast(const float* __restrict__ x, unsigned short* __restrict__ xb) {
  int i = blockIdx.x * 256 + threadIdx.x;   // < NTOK*DIM/8
  const fx4* s = (const fx4*)x + (size_t)i * 2;
  fx4 a = s[0], b = s[1];
  ux4 o;
  o[0] = f2bf(a[0]) | (f2bf(a[1]) << 16);
  o[1] = f2bf(a[2]) | (f2bf(a[3]) << 16);
  o[2] = f2bf(b[0]) | (f2bf(b[1]) << 16);
  o[3] = f2bf(b[2]) | (f2bf(b[3]) << 16);
  ((ux4*)xb)[i] = o;
}

// --------------------------- GEMM 1: h = silu(x @ w1m + b1) -----------------
// Block tile 256 rows x 64 cols, K=1024 over active 64-blocks only.
// LDS 16B chunks swizzled: chunk = row*8 + (seg ^ (row&7)) -> 2-way max.
__global__ __launch_bounds__(256, 2)
void k_gemm1(const unsigned short* __restrict__ xb,
             const float* __restrict__ w1, const float* __restrict__ b1,
             const void* __restrict__ mask1,
             const int* __restrict__ meta, const int* __restrict__ tok_of_row,
             unsigned short* __restrict__ h_c, int c0, int HC)
{
  __shared__ ux4 Ash[2048];                  // 256 rows x 64 k bf16
  __shared__ __align__(16) ux2 Bsh[1024];    // 64 cols x 64 k bf16 (col-major k)
  __shared__ int tok_sh[256];

  const int NCT = HC >> 6;
  const int rt = blockIdx.x / NCT, ct = blockIdx.x % NCT;
  const int base = rt * BM;
  if (base >= meta[48]) return;
  int e = 0;
  #pragma unroll
  for (int i = 1; i < 16; i++) if (meta[32 + i] <= base) e = i;

  const int tid = threadIdx.x;
  tok_sh[tid] = tok_of_row[base + tid];
  const int flag = meta[0];
  const int jg0 = c0 + ct * 64;

  int act[16]; int nact = 0;
  {
    size_t mb = (size_t)e * DIM * HID + jg0;
    for (int db = 0; db < 16; db++)
      if (mask_at(mask1, flag, mb + (size_t)db * 64 * HID)) act[nact++] = db;
  }
  __syncthreads();

  fx4 acc[4][4] = {};
  const int wave = tid >> 6, l = tid & 63;
  const int l16 = l & 15, lhi = l >> 4;

  for (int ii = 0; ii < nact; ii++) {
    const int d0 = act[ii] * 64;
    {   // stage A: one row per thread, gathered via tok_of_row
      int tok = tok_sh[tid];
      const ux4* src = (const ux4*)(xb + (size_t)(tok < 0 ? 0 : tok) * DIM + d0);
      #pragma unroll
      for (int seg = 0; seg < 8; seg++) {
        ux4 v = {0u, 0u, 0u, 0u};
        if (tok >= 0) v = src[seg];
        Ash[tid * 8 + (seg ^ (tid & 7))] = v;
      }
    }
    {   // stage B: 4x4 f32 block per thread, transpose, cast bf16
      const int kb = tid >> 4, jb = tid & 15;
      const int k0 = kb * 4, j0l = jb * 4;
      const float* bp = w1 + ((size_t)e * DIM + d0 + k0) * HID + jg0 + j0l;
      fx4 r0 = *(const fx4*)bp;
      fx4 r1 = *(const fx4*)(bp + HID);
      fx4 r2 = *(const fx4*)(bp + 2 * HID);
      fx4 r3 = *(const fx4*)(bp + 3 * HID);
      #pragma unroll
      for (int jj = 0; jj < 4; jj++) {
        ux2 val;
        val[0] = f2bf(r0[jj]) | (f2bf(r1[jj]) << 16);
        val[1] = f2bf(r2[jj]) | (f2bf(r3[jj]) << 16);
        const int col = j0l + jj;
        Bsh[(col * 8 + ((kb >> 1) ^ (col & 7))) * 2 + (kb & 1)] = val;
      }
    }
    __syncthreads();
    #pragma unroll
    for (int ks = 0; ks < 2; ks++) {
      s8v a[4], b[4];
      const int seg = ks * 4 + lhi;
      #pragma unroll
      for (int m = 0; m < 4; m++) {
        const int row = wave * 64 + m * 16 + l16;
        V16 v; v.u = Ash[row * 8 + (seg ^ (row & 7))]; a[m] = v.s;
      }
      #pragma unroll
      for (int n = 0; n < 4; n++) {
        const int col = n * 16 + l16;
        V16 v; v.u = ((const ux4*)Bsh)[col * 8 + (seg ^ (col & 7))]; b[n] = v.s;
      }
      #pragma unroll
      for (int m = 0; m < 4; m++)
        #pragma unroll
        for (int n = 0; n < 4; n++)
          acc[m][n] = __builtin_amdgcn_mfma_f32_16x16x32_bf16(a[m], b[n], acc[m][n], 0, 0, 0);
    }
    __syncthreads();
  }

  // epilogue: silu(acc + b1) -> bf16 (0 for pad rows so GEMM2 stages cleanly)
  #pragma unroll
  for (int m = 0; m < 4; m++)
    #pragma unroll
    for (int n = 0; n < 4; n++) {
      const int gcol = jg0 + n * 16 + l16;
      const float bb = b1[e * HID + gcol];
      #pragma unroll
      for (int i = 0; i < 4; i++) {
        const int lrow = wave * 64 + m * 16 + lhi * 4 + i;
        float v = acc[m][n][i] + bb;
        float hval = v / (1.0f + expf(-v));
        unsigned short o = (tok_sh[lrow] >= 0) ? (unsigned short)f2bf(hval) : (unsigned short)0;
        h_c[(size_t)(base + lrow) * HC + (ct * 64 + n * 16 + l16)] = o;
      }
    }
}

// --------------------------- GEMM 2: eo += rw * (h @ w2m + b2) --------------
__global__ __launch_bounds__(256, 2)
void k_gemm2(const unsigned short* __restrict__ h_c,
             const float* __restrict__ w2, const float* __restrict__ b2,
             const void* __restrict__ mask2,
             const int* __restrict__ meta, const int* __restrict__ tok_of_row,
             const float* __restrict__ row_w, float* __restrict__ eo,
             int c0, int HC)
{
  __shared__ ux4 Ash[2048];
  __shared__ __align__(16) ux2 Bsh[1024];
  __shared__ int tok_sh[256];
  __shared__ float rw_sh[256];

  const int NCT = 16;   // D/64
  const int rt = blockIdx.x / NCT, ct = blockIdx.x % NCT;
  const int base = rt * BM;
  if (base >= meta[48]) return;
  int e = 0;
  #pragma unroll
  for (int i = 1; i < 16; i++) if (meta[32 + i] <= base) e = i;

  const int tid = threadIdx.x;
  tok_sh[tid] = tok_of_row[base + tid];
  rw_sh[tid]  = row_w[base + tid];
  const int flag = meta[0];
  const int jg0 = ct * 64;
  const int nkb = HC >> 6;

  int act[16]; int nact = 0;
  {
    size_t mb = (size_t)e * HID * DIM + (size_t)c0 * DIM + jg0;
    for (int db = 0; db < nkb; db++)
      if (mask_at(mask2, flag, mb + (size_t)db * 64 * DIM)) act[nact++] = db;
  }
  __syncthreads();

  fx4 acc[4][4] = {};
  const int wave = tid >> 6, l = tid & 63;
  const int l16 = l & 15, lhi = l >> 4;

  for (int ii = 0; ii < nact; ii++) {
    const int d0 = act[ii] * 64;
    {   // stage A: h rows are direct (pad rows were stored as 0)
      const ux4* src = (const ux4*)(h_c + (size_t)(base + tid) * HC + d0);
      #pragma unroll
      for (int seg = 0; seg < 8; seg++)
        Ash[tid * 8 + (seg ^ (tid & 7))] = src[seg];
    }
    {   // stage B from w2
      const int kb = tid >> 4, jb = tid & 15;
      const int k0 = kb * 4, j0l = jb * 4;
      const float* bp = w2 + ((size_t)e * HID + c0 + d0 + k0) * DIM + jg0 + j0l;
      fx4 r0 = *(const fx4*)bp;
      fx4 r1 = *(const fx4*)(bp + DIM);
      fx4 r2 = *(const fx4*)(bp + 2 * DIM);
      fx4 r3 = *(const fx4*)(bp + 3 * DIM);
      #pragma unroll
      for (int jj = 0; jj < 4; jj++) {
        ux2 val;
        val[0] = f2bf(r0[jj]) | (f2bf(r1[jj]) << 16);
        val[1] = f2bf(r2[jj]) | (f2bf(r3[jj]) << 16);
        const int col = j0l + jj;
        Bsh[(col * 8 + ((kb >> 1) ^ (col & 7))) * 2 + (kb & 1)] = val;
      }
    }
    __syncthreads();
    #pragma unroll
    for (int ks = 0; ks < 2; ks++) {
      s8v a[4], b[4];
      const int seg = ks * 4 + lhi;
      #pragma unroll
      for (int m = 0; m < 4; m++) {
        const int row = wave * 64 + m * 16 + l16;
        V16 v; v.u = Ash[row * 8 + (seg ^ (row & 7))]; a[m] = v.s;
      }
      #pragma unroll
      for (int n = 0; n < 4; n++) {
        const int col = n * 16 + l16;
        V16 v; v.u = ((const ux4*)Bsh)[col * 8 + (seg ^ (col & 7))]; b[n] = v.s;
      }
      #pragma unroll
      for (int m = 0; m < 4; m++)
        #pragma unroll
        for (int n = 0; n < 4; n++)
          acc[m][n] = __builtin_amdgcn_mfma_f32_16x16x32_bf16(a[m], b[n], acc[m][n], 0, 0, 0);
    }
    __syncthreads();
  }

  #pragma unroll
  for (int m = 0; m < 4; m++)
    #pragma unroll
    for (int n = 0; n < 4; n++) {
      const int gcol = jg0 + n * 16 + l16;
      const float bb = (c0 == 0) ? b2[e * DIM + gcol] : 0.0f;
      #pragma unroll
      for (int i = 0; i < 4; i++) {
        const int lrow = wave * 64 + m * 16 + lhi * 4 + i;
        const int tok = tok_sh[lrow];
        if (tok >= 0)
          atomicAdd(&eo[(size_t)tok * DIM + gcol], rw_sh[lrow] * (acc[m][n][i] + bb));
      }
    }
}

// --------------------------- cross: out = x + eo @ cwm + cb -----------------
__global__ __launch_bounds__(256, 2)
void k_cross(const float* __restrict__ eo, const float* __restrict__ x,
             const float* __restrict__ cw, const float* __restrict__ cb,
             const void* __restrict__ cmask, const int* __restrict__ meta,
             float* __restrict__ out)
{
  __shared__ ux4 Ash[2048];
  __shared__ __align__(16) ux2 Bsh[1024];

  const int NCT = 16;
  const int rt = blockIdx.x / NCT, ct = blockIdx.x % NCT;
  const int base = rt * BM;
  const int tid = threadIdx.x;
  const int flag = meta[0];
  const int jg0 = ct * 64;

  int act[16]; int nact = 0;
  for (int db = 0; db < 16; db++)
    if (mask_at(cmask, flag, (size_t)db * 64 * DIM + jg0)) act[nact++] = db;

  fx4 acc[4][4] = {};
  const int wave = tid >> 6, l = tid & 63;
  const int l16 = l & 15, lhi = l >> 4;

  for (int ii = 0; ii < nact; ii++) {
    const int d0 = act[ii] * 64;
    {   // stage A from eo (f32 -> bf16)
      const fx4* src = (const fx4*)(eo + (size_t)(base + tid) * DIM + d0);
      #pragma unroll
      for (int seg = 0; seg < 8; seg++) {
        fx4 p = src[seg * 2], q = src[seg * 2 + 1];
        ux4 v;
        v[0] = f2bf(p[0]) | (f2bf(p[1]) << 16);
        v[1] = f2bf(p[2]) | (f2bf(p[3]) << 16);
        v[2] = f2bf(q[0]) | (f2bf(q[1]) << 16);
        v[3] = f2bf(q[2]) | (f2bf(q[3]) << 16);
        Ash[tid * 8 + (seg ^ (tid & 7))] = v;
      }
    }
    {   // stage B from cross_w
      const int kb = tid >> 4, jb = tid & 15;
      const int k0 = kb * 4, j0l = jb * 4;
      const float* bp = cw + (size_t)(d0 + k0) * DIM + jg0 + j0l;
      fx4 r0 = *(const fx4*)bp;
      fx4 r1 = *(const fx4*)(bp + DIM);
      fx4 r2 = *(const fx4*)(bp + 2 * DIM);
      fx4 r3 = *(const fx4*)(bp + 3 * DIM);
      #pragma unroll
      for (int jj = 0; jj < 4; jj++) {
        ux2 val;
        val[0] = f2bf(r0[jj]) | (f2bf(r1[jj]) << 16);
        val[1] = f2bf(r2[jj]) | (f2bf(r3[jj]) << 16);
        const int col = j0l + jj;
        Bsh[(col * 8 + ((kb >> 1) ^ (col & 7))) * 2 + (kb & 1)] = val;
      }
    }
    __syncthreads();
    #pragma unroll
    for (int ks = 0; ks < 2; ks++) {
      s8v a[4], b[4];
      const int seg = ks * 4 + lhi;
      #pragma unroll
      for (int m = 0; m < 4; m++) {
        const int row = wave * 64 + m * 16 + l16;
        V16 v; v.u = Ash[row * 8 + (seg ^ (row & 7))]; a[m] = v.s;
      }
      #pragma unroll
      for (int n = 0; n < 4; n++) {
        const int col = n * 16 + l16;
        V16 v; v.u = ((const ux4*)Bsh)[col * 8 + (seg ^ (col & 7))]; b[n] = v.s;
      }
      #pragma unroll
      for (int m = 0; m < 4; m++)
        #pragma unroll
        for (int n = 0; n < 4; n++)
          acc[m][n] = __builtin_amdgcn_mfma_f32_16x16x32_bf16(a[m], b[n], acc[m][n], 0, 0, 0);
    }
    __syncthreads();
  }

  #pragma unroll
  for (int m = 0; m < 4; m++)
    #pragma unroll
    for (int n = 0; n < 4; n++) {
      const int gcol = jg0 + n * 16 + l16;
      #pragma unroll
      for (int i = 0; i < 4; i++) {
        const int lrow = wave * 64 + m * 16 + lhi * 4 + i;
        const size_t idx = (size_t)(base + lrow) * DIM + gcol;
        out[idx] = acc[m][n][i] + x[idx] + cb[gcol];
      }
    }
}

// ---------------------------------------------------------------------------
extern "C" void kernel_launch(void* const* d_in, const int* in_sizes, int n_in,
                              void* d_out, int out_size, void* d_ws, size_t ws_size,
                              hipStream_t stream)
{
  (void)in_sizes; (void)n_in; (void)out_size;
  const float* x      = (const float*)d_in[0];
  const float* gate_w = (const float*)d_in[1];   // [2,16,1024]
  const float* temp   = (const float*)d_in[2];   // [2]
  const float* w1     = (const float*)d_in[3];   // [16,1024,4096]
  const float* b1     = (const float*)d_in[4];
  const float* w2     = (const float*)d_in[5];   // [16,4096,1024]
  const float* b2     = (const float*)d_in[6];
  const float* cw     = (const float*)d_in[7];   // [1024,1024]
  const float* cb     = (const float*)d_in[8];
  const void*  mask1  = d_in[9];
  const void*  mask2  = d_in[10];
  const void*  cmask  = d_in[11];
  float* out = (float*)d_out;
  char* ws = (char*)d_ws;

  size_t off = 0;
  auto walloc = [&](size_t b) { size_t r = off; off = (off + b + 255) & ~(size_t)255; return r; };
  size_t o_meta = walloc(4096);
  size_t o_t2i  = walloc((size_t)NTOK * 2 * 4);
  size_t o_t2w  = walloc((size_t)NTOK * 2 * 4);
  size_t o_tok  = walloc((size_t)ROWS_CAP * 4);
  size_t o_rww  = walloc((size_t)ROWS_CAP * 4);
  size_t o_xbf  = walloc((size_t)NTOK * DIM * 2);
  size_t o_eo   = walloc((size_t)NTOK * DIM * 4);
  int HC = 1024;                     // H-chunk; shrink if ws is small
  while (HC > 256 && off + (size_t)ROWS_CAP * HC * 2 > ws_size) HC >>= 1;
  size_t o_hc   = walloc((size_t)ROWS_CAP * HC * 2);

  int*            meta = (int*)(ws + o_meta);
  int*            t2i  = (int*)(ws + o_t2i);
  float*          t2w  = (float*)(ws + o_t2w);
  int*            tok  = (int*)(ws + o_tok);
  float*          rww  = (float*)(ws + o_rww);
  unsigned short* xbf  = (unsigned short*)(ws + o_xbf);
  float*          eo   = (float*)(ws + o_eo);
  unsigned short* hc   = (unsigned short*)(ws + o_hc);

  hipMemsetAsync(ws + o_meta, 0, 4096, stream);
  hipMemsetAsync(ws + o_tok, 0xFF, (size_t)ROWS_CAP * 4, stream);  // -1
  hipMemsetAsync(ws + o_eo, 0, (size_t)NTOK * DIM * 4, stream);

  k_detect <<<64, 256, 0, stream>>>((const unsigned int*)mask1, meta);
  k_route  <<<NTOK, 64, 0, stream>>>(x, gate_w + (size_t)1 * NEXP * DIM, temp + 1, t2i, t2w, meta);
  k_offsets<<<1, 64, 0, stream>>>(meta);
  k_assign <<<NTOK / 256, 256, 0, stream>>>(t2i, t2w, meta, tok, rww);
  k_xcast  <<<(NTOK * DIM / 8) / 256, 256, 0, stream>>>(x, xbf);

  const int NRT = ROWS_CAP / BM;   // 80
  for (int c0 = 0; c0 < HID; c0 += HC) {
    k_gemm1<<<NRT * (HC / 64), 256, 0, stream>>>(xbf, w1, b1, mask1, meta, tok, hc, c0, HC);
    k_gemm2<<<NRT * 16, 256, 0, stream>>>(hc, w2, b2, mask2, meta, tok, rww, eo, c0, HC);
  }
  k_cross<<<(NTOK / BM) * 16, 256, 0, stream>>>(eo, x, cw, cb, cmask, meta, out);
}

// Round 2
// 558.053 us; speedup vs baseline: 1.5571x; 1.5571x over previous
//
#include <hip/hip_runtime.h>

// ---------------------------------------------------------------------------
// HierarchicalSparseLayer: top-2 MoE with block-sparse (64x64) masked weights
// B=8192 tokens, D=1024, H=4096, E=16 experts, K=2, + block-sparse cross proj.
// R2: no atomics (pair-row y + combine-in-cross), full-K single pass,
//     precomputed block-mask bitmaps (no scratch arrays, no per-block scans).
// ---------------------------------------------------------------------------

#define NTOK 8192
#define DIM  1024
#define HID  4096
#define NEXP 16
#define BM   256
#define ROWS_CAP (NTOK*2 + NEXP*BM)   // 20480

typedef __attribute__((ext_vector_type(4))) float fx4;
typedef __attribute__((ext_vector_type(4))) unsigned int ux4;
typedef __attribute__((ext_vector_type(2))) unsigned int ux2;
typedef __attribute__((ext_vector_type(8))) short s8v;
union V16 { ux4 u; s8v s; };

__device__ __forceinline__ unsigned int f2bf(float f) {
  unsigned int u = __float_as_uint(f);
  return (u + 0x7fffu + ((u >> 16) & 1u)) >> 16;   // RNE, inputs finite
}

// Mask dtype detected at runtime: flag 0=u8, 1=i32, 2=f32
__device__ __forceinline__ bool mask_at(const void* m, int flag, size_t idx) {
  if (flag == 0) return ((const unsigned char*)m)[idx] != 0;
  if (flag == 1) return ((const int*)m)[idx] != 0;
  return ((const float*)m)[idx] != 0.0f;
}

// --------------------------- mask dtype detection ---------------------------
__global__ void k_detect(const unsigned int* __restrict__ m, int* __restrict__ meta) {
  int bits = 0;
  size_t base = (size_t)blockIdx.x * 4096 + threadIdx.x;
  for (int j = 0; j < 16; j++) {
    unsigned int v = m[base + 256 * j];
    if (v == 0x3f800000u) bits |= 2;
    else if (v > 1u)      bits |= 1;
  }
  if (bits) atomicOr(&meta[1], bits);
}

// --------------------------- routing ---------------------------------------
// meta: [0]=flag [1]=detect bits [8..23]=counts [32..47]=offsets [48]=total
//       [64..79]=slot counters
__global__ void k_route(const float* __restrict__ x,
                        const float* __restrict__ gw,    // gate_w[-1] [16,1024]
                        const float* __restrict__ temp,  // &temperature[-1]
                        int* __restrict__ top2i, float* __restrict__ top2w,
                        int* __restrict__ meta)
{
  const int t = blockIdx.x * 4 + (threadIdx.x >> 6);
  const int l = threadIdx.x & 63;
  const float* xr = x + (size_t)t * DIM;
  float xv[16];
  #pragma unroll
  for (int j = 0; j < 16; j++) xv[j] = xr[l + 64 * j];
  float logit[16];
  #pragma unroll
  for (int e = 0; e < 16; e++) {
    const float* g = gw + (size_t)e * DIM;
    float s = 0.f;
    #pragma unroll
    for (int j = 0; j < 16; j++) s += xv[j] * g[l + 64 * j];
    #pragma unroll
    for (int o = 32; o >= 1; o >>= 1) s += __shfl_xor(s, o);
    logit[e] = s;
  }
  if (l == 0) {
    const float tinv = 1.0f / temp[0];
    int i0 = 0; float v0 = logit[0] * tinv;
    #pragma unroll
    for (int e = 1; e < 16; e++) { float v = logit[e] * tinv; if (v > v0) { v0 = v; i0 = e; } }
    int i1 = -1; float v1 = 0.f; bool first = true;
    #pragma unroll
    for (int e = 0; e < 16; e++) {
      if (e == i0) continue;
      float v = logit[e] * tinv;
      if (first || v > v1) { v1 = v; i1 = e; first = false; }
    }
    float ex = expf(v1 - v0);
    float den = 1.0f + ex;
    top2i[2 * t] = i0; top2i[2 * t + 1] = i1;
    top2w[2 * t] = 1.0f / den; top2w[2 * t + 1] = ex / den;
    atomicAdd(&meta[8 + i0], 1);
    atomicAdd(&meta[8 + i1], 1);
  }
}

__global__ void k_offsets(int* __restrict__ meta) {
  if (threadIdx.x == 0 && blockIdx.x == 0) {
    int o = 0;
    for (int e = 0; e < 16; e++) { meta[32 + e] = o; o += (meta[8 + e] + BM - 1) & ~(BM - 1); }
    meta[48] = o;
    int ev = meta[1];
    meta[0] = (ev & 2) ? 2 : ((ev & 1) ? 0 : 1);
  }
}

__global__ void k_assign(const int* __restrict__ top2i,
                         const float* __restrict__ top2w,
                         int* __restrict__ meta, int* __restrict__ tok_of_row,
                         int* __restrict__ t2row)
{
  int t = blockIdx.x * 256 + threadIdx.x;
  if (t >= NTOK) return;
  #pragma unroll
  for (int k = 0; k < 2; k++) {
    int e = top2i[2 * t + k];
    int slot = atomicAdd(&meta[64 + e], 1);
    int row = meta[32 + e] + slot;
    tok_of_row[row] = t;
    t2row[2 * t + k] = row;
  }
}

// --------------------------- block-mask bitmaps ------------------------------
// bm1[e*64+ct]: bit db (16 k-blocks of D) set if w1 block (e, db, ct) active
// bm2[e*16+ct]: bit db (64 k-blocks of H) set if w2 block (e, db, ct) active
// bmc[ct]:      bit db (16 k-blocks of D) set if cross block (db, ct) active
__global__ void k_bmask(const void* __restrict__ m1, const void* __restrict__ m2,
                        const void* __restrict__ mc, const int* __restrict__ meta,
                        unsigned int* __restrict__ bm1,
                        unsigned long long* __restrict__ bm2,
                        unsigned int* __restrict__ bmc)
{
  const int flag = meta[0];
  const int id = blockIdx.x * 256 + threadIdx.x;
  if (id < 1024) {
    int e = id >> 6, ct = id & 63;
    unsigned int bits = 0;
    size_t basei = (size_t)e * DIM * HID + (size_t)ct * 64;
    for (int db = 0; db < 16; db++)
      if (mask_at(m1, flag, basei + (size_t)db * 64 * HID)) bits |= 1u << db;
    bm1[id] = bits;
  }
  if (id < 256) {
    int e = id >> 4, ct = id & 15;
    unsigned long long bits = 0;
    size_t basei = (size_t)e * HID * DIM + (size_t)ct * 64;
    for (int db = 0; db < 64; db++)
      if (mask_at(m2, flag, basei + (size_t)db * 64 * DIM)) bits |= 1ull << db;
    bm2[id] = bits;
  }
  if (id < 16) {
    unsigned int bits = 0;
    for (int db = 0; db < 16; db++)
      if (mask_at(mc, flag, (size_t)db * 64 * DIM + (size_t)id * 64)) bits |= 1u << db;
    bmc[id] = bits;
  }
}

__global__ void k_xcast(const float* __restrict__ x, unsigned short* __restrict__ xb) {
  int i = blockIdx.x * 256 + threadIdx.x;
  const fx4* s = (const fx4*)x + (size_t)i * 2;
  fx4 a = s[0], b = s[1];
  ux4 o;
  o[0] = f2bf(a[0]) | (f2bf(a[1]) << 16);
  o[1] = f2bf(a[2]) | (f2bf(a[3]) << 16);
  o[2] = f2bf(b[0]) | (f2bf(b[1]) << 16);
  o[3] = f2bf(b[2]) | (f2bf(b[3]) << 16);
  ((ux4*)xb)[i] = o;
}

// --------------------------- GEMM 1: h = silu(x @ w1m + b1) -----------------
__global__ __launch_bounds__(256, 2)
void k_gemm1(const unsigned short* __restrict__ xb,
             const float* __restrict__ w1, const float* __restrict__ b1,
             const unsigned int* __restrict__ bm1,
             const int* __restrict__ meta, const int* __restrict__ tok_of_row,
             unsigned short* __restrict__ h_c, int c0, int HC)
{
  __shared__ ux4 Ash[2048];                  // 256 rows x 64 k bf16 (swizzled)
  __shared__ __align__(16) ux2 Bsh[1024];    // 64 cols x 64 k bf16
  __shared__ int tok_sh[256];

  const int NCT = HC >> 6;
  const int rt = blockIdx.x / NCT, ct = blockIdx.x % NCT;
  const int base = rt * BM;
  if (base >= meta[48]) return;
  int e = 0;
  #pragma unroll
  for (int i = 1; i < 16; i++) if (meta[32 + i] <= base) e = i;

  const int tid = threadIdx.x;
  tok_sh[tid] = tok_of_row[base + tid];
  const int jg0 = c0 + ct * 64;
  unsigned int bits = bm1[e * 64 + (jg0 >> 6)];
  __syncthreads();

  fx4 acc[4][4] = {};
  const int wave = tid >> 6, l = tid & 63;
  const int l16 = l & 15, lhi = l >> 4;

  while (bits) {
    const int db = __ffs(bits) - 1; bits &= bits - 1;
    const int d0 = db * 64;
    {   // stage A: one gathered row per thread
      int tok = tok_sh[tid];
      const ux4* src = (const ux4*)(xb + (size_t)(tok < 0 ? 0 : tok) * DIM + d0);
      #pragma unroll
      for (int seg = 0; seg < 8; seg++) {
        ux4 v = {0u, 0u, 0u, 0u};
        if (tok >= 0) v = src[seg];
        Ash[tid * 8 + (seg ^ (tid & 7))] = v;
      }
    }
    {   // stage B: 4x4 f32 block per thread, transpose, cast bf16
      const int kb = tid >> 4, jb = tid & 15;
      const int k0 = kb * 4, j0l = jb * 4;
      const float* bp = w1 + ((size_t)e * DIM + d0 + k0) * HID + jg0 + j0l;
      fx4 r0 = *(const fx4*)bp;
      fx4 r1 = *(const fx4*)(bp + HID);
      fx4 r2 = *(const fx4*)(bp + 2 * HID);
      fx4 r3 = *(const fx4*)(bp + 3 * HID);
      #pragma unroll
      for (int jj = 0; jj < 4; jj++) {
        ux2 val;
        val[0] = f2bf(r0[jj]) | (f2bf(r1[jj]) << 16);
        val[1] = f2bf(r2[jj]) | (f2bf(r3[jj]) << 16);
        const int col = j0l + jj;
        Bsh[(col * 8 + ((kb >> 1) ^ (col & 7))) * 2 + (kb & 1)] = val;
      }
    }
    __syncthreads();
    #pragma unroll
    for (int ks = 0; ks < 2; ks++) {
      s8v a[4], b[4];
      const int seg = ks * 4 + lhi;
      #pragma unroll
      for (int m = 0; m < 4; m++) {
        const int row = wave * 64 + m * 16 + l16;
        V16 v; v.u = Ash[row * 8 + (seg ^ (row & 7))]; a[m] = v.s;
      }
      #pragma unroll
      for (int n = 0; n < 4; n++) {
        const int col = n * 16 + l16;
        V16 v; v.u = ((const ux4*)Bsh)[col * 8 + (seg ^ (col & 7))]; b[n] = v.s;
      }
      #pragma unroll
      for (int m = 0; m < 4; m++)
        #pragma unroll
        for (int n = 0; n < 4; n++)
          acc[m][n] = __builtin_amdgcn_mfma_f32_16x16x32_bf16(a[m], b[n], acc[m][n], 0, 0, 0);
    }
    __syncthreads();
  }

  #pragma unroll
  for (int m = 0; m < 4; m++)
    #pragma unroll
    for (int n = 0; n < 4; n++) {
      const int gcol = jg0 + n * 16 + l16;
      const float bb = b1[e * HID + gcol];
      #pragma unroll
      for (int i = 0; i < 4; i++) {
        const int lrow = wave * 64 + m * 16 + lhi * 4 + i;
        float v = acc[m][n][i] + bb;
        float hval = v / (1.0f + expf(-v));
        unsigned short o = (tok_sh[lrow] >= 0) ? (unsigned short)f2bf(hval) : (unsigned short)0;
        h_c[(size_t)(base + lrow) * HC + (ct * 64 + n * 16 + l16)] = o;
      }
    }
}

// --------------------------- GEMM 2: y = h @ w2m + b2 (pair rows) -----------
__global__ __launch_bounds__(256, 2)
void k_gemm2(const unsigned short* __restrict__ h_c,
             const float* __restrict__ w2, const float* __restrict__ b2,
             const unsigned long long* __restrict__ bm2,
             const int* __restrict__ meta, float* __restrict__ y,
             int c0, int HC)
{
  __shared__ ux4 Ash[2048];
  __shared__ __align__(16) ux2 Bsh[1024];

  const int NCT = 16;   // D/64
  const int rt = blockIdx.x / NCT, ct = blockIdx.x % NCT;
  const int base = rt * BM;
  if (base >= meta[48]) return;
  int e = 0;
  #pragma unroll
  for (int i = 1; i < 16; i++) if (meta[32 + i] <= base) e = i;

  const int tid = threadIdx.x;
  const int jg0 = ct * 64;
  const int nkb = HC >> 6;
  unsigned long long bits = bm2[e * 16 + ct] >> (c0 >> 6);
  if (nkb < 64) bits &= (1ull << nkb) - 1;

  fx4 acc[4][4] = {};
  const int wave = tid >> 6, l = tid & 63;
  const int l16 = l & 15, lhi = l >> 4;

  while (bits) {
    const int db = __ffsll((unsigned long long)bits) - 1; bits &= bits - 1;
    const int d0 = db * 64;
    {   // stage A: h rows direct (pad rows stored as 0)
      const ux4* src = (const ux4*)(h_c + (size_t)(base + tid) * HC + d0);
      #pragma unroll
      for (int seg = 0; seg < 8; seg++)
        Ash[tid * 8 + (seg ^ (tid & 7))] = src[seg];
    }
    {   // stage B from w2
      const int kb = tid >> 4, jb = tid & 15;
      const int k0 = kb * 4, j0l = jb * 4;
      const float* bp = w2 + ((size_t)e * HID + c0 + d0 + k0) * DIM + jg0 + j0l;
      fx4 r0 = *(const fx4*)bp;
      fx4 r1 = *(const fx4*)(bp + DIM);
      fx4 r2 = *(const fx4*)(bp + 2 * DIM);
      fx4 r3 = *(const fx4*)(bp + 3 * DIM);
      #pragma unroll
      for (int jj = 0; jj < 4; jj++) {
        ux2 val;
        val[0] = f2bf(r0[jj]) | (f2bf(r1[jj]) << 16);
        val[1] = f2bf(r2[jj]) | (f2bf(r3[jj]) << 16);
        const int col = j0l + jj;
        Bsh[(col * 8 + ((kb >> 1) ^ (col & 7))) * 2 + (kb & 1)] = val;
      }
    }
    __syncthreads();
    #pragma unroll
    for (int ks = 0; ks < 2; ks++) {
      s8v a[4], b[4];
      const int seg = ks * 4 + lhi;
      #pragma unroll
      for (int m = 0; m < 4; m++) {
        const int row = wave * 64 + m * 16 + l16;
        V16 v; v.u = Ash[row * 8 + (seg ^ (row & 7))]; a[m] = v.s;
      }
      #pragma unroll
      for (int n = 0; n < 4; n++) {
        const int col = n * 16 + l16;
        V16 v; v.u = ((const ux4*)Bsh)[col * 8 + (seg ^ (col & 7))]; b[n] = v.s;
      }
      #pragma unroll
      for (int m = 0; m < 4; m++)
        #pragma unroll
        for (int n = 0; n < 4; n++)
          acc[m][n] = __builtin_amdgcn_mfma_f32_16x16x32_bf16(a[m], b[n], acc[m][n], 0, 0, 0);
    }
    __syncthreads();
  }

  // epilogue: y = acc + b2 (c0==0) or y += acc. Non-atomic: block owns tile,
  // chunk launches are stream-serialized.
  #pragma unroll
  for (int m = 0; m < 4; m++)
    #pragma unroll
    for (int n = 0; n < 4; n++) {
      const int gcol = jg0 + n * 16 + l16;
      const float bb = b2[e * DIM + gcol];
      #pragma unroll
      for (int i = 0; i < 4; i++) {
        const int lrow = wave * 64 + m * 16 + lhi * 4 + i;
        float* p = &y[(size_t)(base + lrow) * DIM + gcol];
        if (c0 == 0) *p = acc[m][n][i] + bb;
        else         *p += acc[m][n][i];
      }
    }
}

// --------------------------- cross: out = x + eo @ cwm + cb -----------------
// eo rows are formed on the fly: eo[tok] = w0*y[r0] + w1*y[r1]
__global__ __launch_bounds__(256, 2)
void k_cross(const float* __restrict__ y, const float* __restrict__ x,
             const float* __restrict__ cw, const float* __restrict__ cb,
             const unsigned int* __restrict__ bmc,
             const int* __restrict__ t2row, const float* __restrict__ t2w,
             float* __restrict__ out)
{
  __shared__ ux4 Ash[2048];
  __shared__ __align__(16) ux2 Bsh[1024];

  const int NCT = 16;
  const int rt = blockIdx.x / NCT, ct = blockIdx.x % NCT;
  const int base = rt * BM;
  const int tid = threadIdx.x;
  const int jg0 = ct * 64;
  unsigned int bits0 = bmc[ct];

  const int tok = base + tid;
  const int r0 = t2row[2 * tok], r1 = t2row[2 * tok + 1];
  const float w0 = t2w[2 * tok], w1 = t2w[2 * tok + 1];

  fx4 acc[4][4] = {};
  const int wave = tid >> 6, l = tid & 63;
  const int l16 = l & 15, lhi = l >> 4;

  unsigned int bits = bits0;
  while (bits) {
    const int db = __ffs(bits) - 1; bits &= bits - 1;
    const int d0 = db * 64;
    {   // stage A: combine two pair rows -> bf16
      const fx4* s0 = (const fx4*)(y + (size_t)r0 * DIM + d0);
      const fx4* s1 = (const fx4*)(y + (size_t)r1 * DIM + d0);
      #pragma unroll
      for (int seg = 0; seg < 8; seg++) {
        fx4 p = w0 * s0[seg * 2]     + w1 * s1[seg * 2];
        fx4 q = w0 * s0[seg * 2 + 1] + w1 * s1[seg * 2 + 1];
        ux4 v;
        v[0] = f2bf(p[0]) | (f2bf(p[1]) << 16);
        v[1] = f2bf(p[2]) | (f2bf(p[3]) << 16);
        v[2] = f2bf(q[0]) | (f2bf(q[1]) << 16);
        v[3] = f2bf(q[2]) | (f2bf(q[3]) << 16);
        Ash[tid * 8 + (seg ^ (tid & 7))] = v;
      }
    }
    {   // stage B from cross_w
      const int kb = tid >> 4, jb = tid & 15;
      const int k0 = kb * 4, j0l = jb * 4;
      const float* bp = cw + (size_t)(d0 + k0) * DIM + jg0 + j0l;
      fx4 r0v = *(const fx4*)bp;
      fx4 r1v = *(const fx4*)(bp + DIM);
      fx4 r2v = *(const fx4*)(bp + 2 * DIM);
      fx4 r3v = *(const fx4*)(bp + 3 * DIM);
      #pragma unroll
      for (int jj = 0; jj < 4; jj++) {
        ux2 val;
        val[0] = f2bf(r0v[jj]) | (f2bf(r1v[jj]) << 16);
        val[1] = f2bf(r2v[jj]) | (f2bf(r3v[jj]) << 16);
        const int col = j0l + jj;
        Bsh[(col * 8 + ((kb >> 1) ^ (col & 7))) * 2 + (kb & 1)] = val;
      }
    }
    __syncthreads();
    #pragma unroll
    for (int ks = 0; ks < 2; ks++) {
      s8v a[4], b[4];
      const int seg = ks * 4 + lhi;
      #pragma unroll
      for (int m = 0; m < 4; m++) {
        const int row = wave * 64 + m * 16 + l16;
        V16 v; v.u = Ash[row * 8 + (seg ^ (row & 7))]; a[m] = v.s;
      }
      #pragma unroll
      for (int n = 0; n < 4; n++) {
        const int col = n * 16 + l16;
        V16 v; v.u = ((const ux4*)Bsh)[col * 8 + (seg ^ (col & 7))]; b[n] = v.s;
      }
      #pragma unroll
      for (int m = 0; m < 4; m++)
        #pragma unroll
        for (int n = 0; n < 4; n++)
          acc[m][n] = __builtin_amdgcn_mfma_f32_16x16x32_bf16(a[m], b[n], acc[m][n], 0, 0, 0);
    }
    __syncthreads();
  }

  #pragma unroll
  for (int m = 0; m < 4; m++)
    #pragma unroll
    for (int n = 0; n < 4; n++) {
      const int gcol = jg0 + n * 16 + l16;
      #pragma unroll
      for (int i = 0; i < 4; i++) {
        const int lrow = wave * 64 + m * 16 + lhi * 4 + i;
        const size_t idx = (size_t)(base + lrow) * DIM + gcol;
        out[idx] = acc[m][n][i] + x[idx] + cb[gcol];
      }
    }
}

// ---------------------------------------------------------------------------
extern "C" void kernel_launch(void* const* d_in, const int* in_sizes, int n_in,
                              void* d_out, int out_size, void* d_ws, size_t ws_size,
                              hipStream_t stream)
{
  (void)in_sizes; (void)n_in; (void)out_size;
  const float* x      = (const float*)d_in[0];
  const float* gate_w = (const float*)d_in[1];   // [2,16,1024]
  const float* temp   = (const float*)d_in[2];   // [2]
  const float* w1     = (const float*)d_in[3];   // [16,1024,4096]
  const float* b1     = (const float*)d_in[4];
  const float* w2     = (const float*)d_in[5];   // [16,4096,1024]
  const float* b2     = (const float*)d_in[6];
  const float* cw     = (const float*)d_in[7];   // [1024,1024]
  const float* cb     = (const float*)d_in[8];
  const void*  mask1  = d_in[9];
  const void*  mask2  = d_in[10];
  const void*  cmask  = d_in[11];
  float* out = (float*)d_out;
  char* ws = (char*)d_ws;

  size_t off = 0;
  auto walloc = [&](size_t b) { size_t r = off; off = (off + b + 255) & ~(size_t)255; return r; };
  size_t o_meta = walloc(4096);
  size_t o_bm1  = walloc(1024 * 4);
  size_t o_bm2  = walloc(256 * 8);
  size_t o_bmc  = walloc(64 * 4);
  size_t o_t2i  = walloc((size_t)NTOK * 2 * 4);
  size_t o_t2w  = walloc((size_t)NTOK * 2 * 4);
  size_t o_t2r  = walloc((size_t)NTOK * 2 * 4);
  size_t o_tok  = walloc((size_t)ROWS_CAP * 4);
  size_t o_xbf  = walloc((size_t)NTOK * DIM * 2);
  size_t o_y    = walloc((size_t)ROWS_CAP * DIM * 4);
  int HC = HID;
  while (HC > 256 && off + (size_t)ROWS_CAP * HC * 2 > ws_size) HC >>= 1;
  size_t o_hc   = walloc((size_t)ROWS_CAP * HC * 2);

  int*                meta = (int*)(ws + o_meta);
  unsigned int*       bm1  = (unsigned int*)(ws + o_bm1);
  unsigned long long* bm2  = (unsigned long long*)(ws + o_bm2);
  unsigned int*       bmc  = (unsigned int*)(ws + o_bmc);
  int*                t2i  = (int*)(ws + o_t2i);
  float*              t2w  = (float*)(ws + o_t2w);
  int*                t2r  = (int*)(ws + o_t2r);
  int*                tok  = (int*)(ws + o_tok);
  unsigned short*     xbf  = (unsigned short*)(ws + o_xbf);
  float*              y    = (float*)(ws + o_y);
  unsigned short*     hc   = (unsigned short*)(ws + o_hc);

  hipMemsetAsync(ws + o_meta, 0, 4096, stream);
  hipMemsetAsync(ws + o_tok, 0xFF, (size_t)ROWS_CAP * 4, stream);  // -1

  k_detect <<<64, 256, 0, stream>>>((const unsigned int*)mask1, meta);
  k_route  <<<NTOK / 4, 256, 0, stream>>>(x, gate_w + (size_t)1 * NEXP * DIM, temp + 1, t2i, t2w, meta);
  k_offsets<<<1, 64, 0, stream>>>(meta);
  k_assign <<<NTOK / 256, 256, 0, stream>>>(t2i, t2w, meta, tok, t2r);
  k_bmask  <<<4, 256, 0, stream>>>(mask1, mask2, cmask, meta, bm1, bm2, bmc);
  k_xcast  <<<(NTOK * DIM / 8) / 256, 256, 0, stream>>>(x, xbf);

  const int NRT = ROWS_CAP / BM;   // 80
  for (int c0 = 0; c0 < HID; c0 += HC) {
    k_gemm1<<<NRT * (HC / 64), 256, 0, stream>>>(xbf, w1, b1, bm1, meta, tok, hc, c0, HC);
    k_gemm2<<<NRT * 16, 256, 0, stream>>>(hc, w2, b2, bm2, meta, y, c0, HC);
  }
  k_cross<<<(NTOK / BM) * 16, 256, 0, stream>>>(y, x, cw, cb, bmc, t2r, t2w, out);
}

// Round 3
// 515.529 us; speedup vs baseline: 1.6855x; 1.0825x over previous
//
#include <hip/hip_runtime.h>

// ---------------------------------------------------------------------------
// HierarchicalSparseLayer: top-2 MoE with block-sparse (64x64) masked weights
// B=8192 tokens, D=1024, H=4096, E=16 experts, K=2, + block-sparse cross proj.
// R3: double-buffered K-loop (T3-min), A-staging via global_load_lds with
//     pre-swizzled per-lane source addresses, LDS-restaged h epilogue,
//     v_cvt_pk_bf16_f32 for the B cast.
// ---------------------------------------------------------------------------

#define NTOK 8192
#define DIM  1024
#define HID  4096
#define NEXP 16
#define BM   256
#define ROWS_CAP (NTOK*2 + NEXP*BM)   // 20480

typedef __attribute__((ext_vector_type(4))) float fx4;
typedef __attribute__((ext_vector_type(4))) unsigned int ux4;
typedef __attribute__((ext_vector_type(2))) unsigned int ux2;
typedef __attribute__((ext_vector_type(8))) short s8v;
union V16 { ux4 u; s8v s; };

__device__ __forceinline__ unsigned int f2bf(float f) {
  unsigned int u = __float_as_uint(f);
  return (u + 0x7fffu + ((u >> 16) & 1u)) >> 16;   // RNE, inputs finite
}

__device__ __forceinline__ unsigned int cvt_pk(float lo, float hi) {
  unsigned int r;
  asm("v_cvt_pk_bf16_f32 %0, %1, %2" : "=v"(r) : "v"(lo), "v"(hi));
  return r;
}

// Mask dtype detected at runtime: flag 0=u8, 1=i32, 2=f32
__device__ __forceinline__ bool mask_at(const void* m, int flag, size_t idx) {
  if (flag == 0) return ((const unsigned char*)m)[idx] != 0;
  if (flag == 1) return ((const int*)m)[idx] != 0;
  return ((const float*)m)[idx] != 0.0f;
}

// --------------------------- mask dtype detection ---------------------------
__global__ void k_detect(const unsigned int* __restrict__ m, int* __restrict__ meta) {
  int bits = 0;
  size_t base = (size_t)blockIdx.x * 4096 + threadIdx.x;
  for (int j = 0; j < 16; j++) {
    unsigned int v = m[base + 256 * j];
    if (v == 0x3f800000u) bits |= 2;
    else if (v > 1u)      bits |= 1;
  }
  if (bits) atomicOr(&meta[1], bits);
}

// --------------------------- routing ---------------------------------------
// meta: [0]=flag [1]=detect bits [8..23]=counts [32..47]=offsets [48]=total
//       [64..79]=slot counters
__global__ void k_route(const float* __restrict__ x,
                        const float* __restrict__ gw,    // gate_w[-1] [16,1024]
                        const float* __restrict__ temp,  // &temperature[-1]
                        int* __restrict__ top2i, float* __restrict__ top2w,
                        int* __restrict__ meta)
{
  const int t = blockIdx.x * 4 + (threadIdx.x >> 6);
  const int l = threadIdx.x & 63;
  const float* xr = x + (size_t)t * DIM;
  float xv[16];
  #pragma unroll
  for (int j = 0; j < 16; j++) xv[j] = xr[l + 64 * j];
  float logit[16];
  #pragma unroll
  for (int e = 0; e < 16; e++) {
    const float* g = gw + (size_t)e * DIM;
    float s = 0.f;
    #pragma unroll
    for (int j = 0; j < 16; j++) s += xv[j] * g[l + 64 * j];
    #pragma unroll
    for (int o = 32; o >= 1; o >>= 1) s += __shfl_xor(s, o);
    logit[e] = s;
  }
  if (l == 0) {
    const float tinv = 1.0f / temp[0];
    int i0 = 0; float v0 = logit[0] * tinv;
    #pragma unroll
    for (int e = 1; e < 16; e++) { float v = logit[e] * tinv; if (v > v0) { v0 = v; i0 = e; } }
    int i1 = -1; float v1 = 0.f; bool first = true;
    #pragma unroll
    for (int e = 0; e < 16; e++) {
      if (e == i0) continue;
      float v = logit[e] * tinv;
      if (first || v > v1) { v1 = v; i1 = e; first = false; }
    }
    float ex = expf(v1 - v0);
    float den = 1.0f + ex;
    top2i[2 * t] = i0; top2i[2 * t + 1] = i1;
    top2w[2 * t] = 1.0f / den; top2w[2 * t + 1] = ex / den;
    atomicAdd(&meta[8 + i0], 1);
    atomicAdd(&meta[8 + i1], 1);
  }
}

__global__ void k_offsets(int* __restrict__ meta) {
  if (threadIdx.x == 0 && blockIdx.x == 0) {
    int o = 0;
    for (int e = 0; e < 16; e++) { meta[32 + e] = o; o += (meta[8 + e] + BM - 1) & ~(BM - 1); }
    meta[48] = o;
    int ev = meta[1];
    meta[0] = (ev & 2) ? 2 : ((ev & 1) ? 0 : 1);
  }
}

__global__ void k_assign(const int* __restrict__ top2i,
                         const float* __restrict__ top2w,
                         int* __restrict__ meta, int* __restrict__ tok_of_row,
                         int* __restrict__ t2row)
{
  int t = blockIdx.x * 256 + threadIdx.x;
  if (t >= NTOK) return;
  #pragma unroll
  for (int k = 0; k < 2; k++) {
    int e = top2i[2 * t + k];
    int slot = atomicAdd(&meta[64 + e], 1);
    int row = meta[32 + e] + slot;
    tok_of_row[row] = t;
    t2row[2 * t + k] = row;
  }
}

// --------------------------- block-mask bitmaps ------------------------------
__global__ void k_bmask(const void* __restrict__ m1, const void* __restrict__ m2,
                        const void* __restrict__ mc, const int* __restrict__ meta,
                        unsigned int* __restrict__ bm1,
                        unsigned long long* __restrict__ bm2,
                        unsigned int* __restrict__ bmc)
{
  const int flag = meta[0];
  const int id = blockIdx.x * 256 + threadIdx.x;
  if (id < 1024) {
    int e = id >> 6, ct = id & 63;
    unsigned int bits = 0;
    size_t basei = (size_t)e * DIM * HID + (size_t)ct * 64;
    for (int db = 0; db < 16; db++)
      if (mask_at(m1, flag, basei + (size_t)db * 64 * HID)) bits |= 1u << db;
    bm1[id] = bits;
  }
  if (id < 256) {
    int e = id >> 4, ct = id & 15;
    unsigned long long bits = 0;
    size_t basei = (size_t)e * HID * DIM + (size_t)ct * 64;
    for (int db = 0; db < 64; db++)
      if (mask_at(m2, flag, basei + (size_t)db * 64 * DIM)) bits |= 1ull << db;
    bm2[id] = bits;
  }
  if (id < 16) {
    unsigned int bits = 0;
    for (int db = 0; db < 16; db++)
      if (mask_at(mc, flag, (size_t)db * 64 * DIM + (size_t)id * 64)) bits |= 1u << db;
    bmc[id] = bits;
  }
}

__global__ void k_xcast(const float* __restrict__ x, unsigned short* __restrict__ xb) {
  int i = blockIdx.x * 256 + threadIdx.x;
  const fx4* s = (const fx4*)x + (size_t)i * 2;
  fx4 a = s[0], b = s[1];
  ux4 o;
  o[0] = f2bf(a[0]) | (f2bf(a[1]) << 16);
  o[1] = f2bf(a[2]) | (f2bf(a[3]) << 16);
  o[2] = f2bf(b[0]) | (f2bf(b[1]) << 16);
  o[3] = f2bf(b[2]) | (f2bf(b[3]) << 16);
  ((ux4*)xb)[i] = o;
}

// --------------------------- GEMM 1: h = silu(x @ w1m + b1) -----------------
// Double-buffered: A via global_load_lds (pre-swizzled per-lane source),
// B via reg-staged f32 + cvt_pk, one barrier per K-block.
__global__ __launch_bounds__(256, 2)
void k_gemm1(const unsigned short* __restrict__ xb,
             const float* __restrict__ w1, const float* __restrict__ b1,
             const unsigned int* __restrict__ bm1,
             const int* __restrict__ meta, const int* __restrict__ tok_of_row,
             unsigned short* __restrict__ h_c, int c0, int HC)
{
  __shared__ ux4 Ash[2][2048];                  // 2 x (256 rows x 64 k bf16)
  __shared__ __align__(16) ux2 Bsh[2][1024];    // 2 x (64 cols x 64 k bf16)

  const int NCT = HC >> 6;
  const int rt = blockIdx.x / NCT, ct = blockIdx.x % NCT;
  const int base = rt * BM;
  if (base >= meta[48]) return;
  int e = 0;
  #pragma unroll
  for (int i = 1; i < 16; i++) if (meta[32 + i] <= base) e = i;

  const int tid = threadIdx.x;
  const int wv = tid >> 6;
  const int jg0 = c0 + ct * 64;
  unsigned int bits = bm1[e * 64 + (jg0 >> 6)];

  // DMA source offsets: LDS chunk c = i*256 + tid; row = c>>3 = i*32 + tid>>3;
  // stored seg at slot = (c&7) ^ (row&7)  (the XOR swizzle, applied on source)
  const unsigned int sseg = (unsigned int)(((tid & 7) ^ ((tid >> 3) & 7)) * 16);
  unsigned int aoff[8];
  #pragma unroll
  for (int i = 0; i < 8; i++) {
    int tok = tok_of_row[base + i * 32 + (tid >> 3)];
    if (tok < 0) tok = 0;                       // pad rows: finite garbage, unused
    aoff[i] = (unsigned int)tok * (DIM * 2) + sseg;
  }

  const int l = tid & 63, l16 = l & 15, lhi = l >> 4;
  const int kb = tid >> 4, jb = tid & 15;

  fx4 acc[4][4] = {};

  auto STAGE_A = [&](int b, int d0) {
    const char* gp = (const char*)xb + (d0 << 1);
    #pragma unroll
    for (int i = 0; i < 8; i++)
      __builtin_amdgcn_global_load_lds(
        (const __attribute__((address_space(1))) unsigned int*)(gp + aoff[i]),
        (__attribute__((address_space(3))) unsigned int*)&Ash[b][i * 256 + wv * 64],
        16, 0, 0);
  };
  auto LOAD_B = [&](fx4* r, int d0) {
    const float* bp = w1 + ((size_t)e * DIM + d0 + kb * 4) * HID + jg0 + jb * 4;
    r[0] = *(const fx4*)bp;
    r[1] = *(const fx4*)(bp + HID);
    r[2] = *(const fx4*)(bp + 2 * HID);
    r[3] = *(const fx4*)(bp + 3 * HID);
  };
  auto WRITE_B = [&](int b, const fx4* r) {
    #pragma unroll
    for (int jj = 0; jj < 4; jj++) {
      ux2 val;
      val[0] = cvt_pk(r[0][jj], r[1][jj]);
      val[1] = cvt_pk(r[2][jj], r[3][jj]);
      const int col = jb * 4 + jj;
      Bsh[b][(col * 8 + ((kb >> 1) ^ (col & 7))) * 2 + (kb & 1)] = val;
    }
  };
  auto COMPUTE = [&](int b) {
    #pragma unroll
    for (int ks = 0; ks < 2; ks++) {
      s8v a[4], bb[4];
      const int seg = ks * 4 + lhi;
      #pragma unroll
      for (int m = 0; m < 4; m++) {
        const int row = wv * 64 + m * 16 + l16;
        V16 v; v.u = Ash[b][row * 8 + (seg ^ (row & 7))]; a[m] = v.s;
      }
      #pragma unroll
      for (int n = 0; n < 4; n++) {
        const int col = n * 16 + l16;
        V16 v; v.u = ((const ux4*)&Bsh[b][0])[col * 8 + (seg ^ (col & 7))]; bb[n] = v.s;
      }
      #pragma unroll
      for (int m = 0; m < 4; m++)
        #pragma unroll
        for (int n = 0; n < 4; n++)
          acc[m][n] = __builtin_amdgcn_mfma_f32_16x16x32_bf16(a[m], bb[n], acc[m][n], 0, 0, 0);
    }
  };

  if (bits) {
    int d0 = (__ffs(bits) - 1) << 6; bits &= bits - 1;
    {
      fx4 br[4];
      STAGE_A(0, d0);
      LOAD_B(br, d0);
      WRITE_B(0, br);
    }
    __syncthreads();
    int cur = 0;
    for (;;) {
      int nd0 = -1;
      fx4 br2[4];
      if (bits) { nd0 = (__ffs(bits) - 1) << 6; bits &= bits - 1; }
      if (nd0 >= 0) { STAGE_A(cur ^ 1, nd0); LOAD_B(br2, nd0); }
      COMPUTE(cur);
      if (nd0 >= 0) WRITE_B(cur ^ 1, br2);
      __syncthreads();
      cur ^= 1;
      if (nd0 < 0) break;
    }
  }

  // epilogue: silu(acc + b1) -> LDS bf16 tile -> coalesced 16B dump
  unsigned short* hs = (unsigned short*)&Ash[0][0];
  __syncthreads();
  #pragma unroll
  for (int m = 0; m < 4; m++)
    #pragma unroll
    for (int n = 0; n < 4; n++) {
      const int gcol = jg0 + n * 16 + l16;
      const float bbv = b1[e * HID + gcol];
      #pragma unroll
      for (int i = 0; i < 4; i++) {
        const int row = wv * 64 + m * 16 + lhi * 4 + i;
        float v = acc[m][n][i] + bbv;
        float hval = v / (1.0f + expf(-v));
        hs[row * 64 + n * 16 + l16] = (unsigned short)f2bf(hval);
      }
    }
  __syncthreads();
  {
    const ux4* s = (const ux4*)hs;
    #pragma unroll
    for (int j = 0; j < 8; j++) {
      const int c2 = j * 256 + tid;
      const int row = c2 >> 3;
      *(ux4*)(h_c + (size_t)(base + row) * HC + ct * 64 + (c2 & 7) * 8) = s[c2];
    }
  }
}

// --------------------------- GEMM 2: y = h @ w2m + b2 (pair rows) -----------
__global__ __launch_bounds__(256, 2)
void k_gemm2(const unsigned short* __restrict__ h_c,
             const float* __restrict__ w2, const float* __restrict__ b2,
             const unsigned long long* __restrict__ bm2,
             const int* __restrict__ meta, float* __restrict__ y,
             int c0, int HC)
{
  __shared__ ux4 Ash[2][2048];
  __shared__ __align__(16) ux2 Bsh[2][1024];

  const int NCT = 16;   // D/64
  const int rt = blockIdx.x / NCT, ct = blockIdx.x % NCT;
  const int base = rt * BM;
  if (base >= meta[48]) return;
  int e = 0;
  #pragma unroll
  for (int i = 1; i < 16; i++) if (meta[32 + i] <= base) e = i;

  const int tid = threadIdx.x;
  const int wv = tid >> 6;
  const int jg0 = ct * 64;
  const int nkb = HC >> 6;
  unsigned long long bits = bm2[e * 16 + ct] >> (c0 >> 6);
  if (nkb < 64) bits &= (1ull << nkb) - 1;

  const unsigned int sseg = (unsigned int)(((tid & 7) ^ ((tid >> 3) & 7)) * 16);
  unsigned int aoff[8];
  #pragma unroll
  for (int i = 0; i < 8; i++)
    aoff[i] = (unsigned int)(base + i * 32 + (tid >> 3)) * (unsigned int)(HC * 2) + sseg;

  const int l = tid & 63, l16 = l & 15, lhi = l >> 4;
  const int kb = tid >> 4, jb = tid & 15;

  fx4 acc[4][4] = {};

  auto STAGE_A = [&](int b, int d0) {
    const char* gp = (const char*)h_c + (d0 << 1);
    #pragma unroll
    for (int i = 0; i < 8; i++)
      __builtin_amdgcn_global_load_lds(
        (const __attribute__((address_space(1))) unsigned int*)(gp + aoff[i]),
        (__attribute__((address_space(3))) unsigned int*)&Ash[b][i * 256 + wv * 64],
        16, 0, 0);
  };
  auto LOAD_B = [&](fx4* r, int d0) {
    const float* bp = w2 + ((size_t)e * HID + c0 + d0 + kb * 4) * DIM + jg0 + jb * 4;
    r[0] = *(const fx4*)bp;
    r[1] = *(const fx4*)(bp + DIM);
    r[2] = *(const fx4*)(bp + 2 * DIM);
    r[3] = *(const fx4*)(bp + 3 * DIM);
  };
  auto WRITE_B = [&](int b, const fx4* r) {
    #pragma unroll
    for (int jj = 0; jj < 4; jj++) {
      ux2 val;
      val[0] = cvt_pk(r[0][jj], r[1][jj]);
      val[1] = cvt_pk(r[2][jj], r[3][jj]);
      const int col = jb * 4 + jj;
      Bsh[b][(col * 8 + ((kb >> 1) ^ (col & 7))) * 2 + (kb & 1)] = val;
    }
  };
  auto COMPUTE = [&](int b) {
    #pragma unroll
    for (int ks = 0; ks < 2; ks++) {
      s8v a[4], bb[4];
      const int seg = ks * 4 + lhi;
      #pragma unroll
      for (int m = 0; m < 4; m++) {
        const int row = wv * 64 + m * 16 + l16;
        V16 v; v.u = Ash[b][row * 8 + (seg ^ (row & 7))]; a[m] = v.s;
      }
      #pragma unroll
      for (int n = 0; n < 4; n++) {
        const int col = n * 16 + l16;
        V16 v; v.u = ((const ux4*)&Bsh[b][0])[col * 8 + (seg ^ (col & 7))]; bb[n] = v.s;
      }
      #pragma unroll
      for (int m = 0; m < 4; m++)
        #pragma unroll
        for (int n = 0; n < 4; n++)
          acc[m][n] = __builtin_amdgcn_mfma_f32_16x16x32_bf16(a[m], bb[n], acc[m][n], 0, 0, 0);
    }
  };

  if (bits) {
    int d0 = (__ffsll(bits) - 1) << 6; bits &= bits - 1;
    {
      fx4 br[4];
      STAGE_A(0, d0);
      LOAD_B(br, d0);
      WRITE_B(0, br);
    }
    __syncthreads();
    int cur = 0;
    for (;;) {
      int nd0 = -1;
      fx4 br2[4];
      if (bits) { nd0 = (__ffsll(bits) - 1) << 6; bits &= bits - 1; }
      if (nd0 >= 0) { STAGE_A(cur ^ 1, nd0); LOAD_B(br2, nd0); }
      COMPUTE(cur);
      if (nd0 >= 0) WRITE_B(cur ^ 1, br2);
      __syncthreads();
      cur ^= 1;
      if (nd0 < 0) break;
    }
  }

  // epilogue: y = acc + b2 (c0==0) or y += acc (chunk accumulation)
  #pragma unroll
  for (int m = 0; m < 4; m++)
    #pragma unroll
    for (int n = 0; n < 4; n++) {
      const int gcol = jg0 + n * 16 + l16;
      const float bbv = b2[e * DIM + gcol];
      #pragma unroll
      for (int i = 0; i < 4; i++) {
        const int lrow = wv * 64 + m * 16 + lhi * 4 + i;
        float* p = &y[(size_t)(base + lrow) * DIM + gcol];
        if (c0 == 0) *p = acc[m][n][i] + bbv;
        else         *p += acc[m][n][i];
      }
    }
}

// --------------------------- cross: out = x + eo @ cwm + cb -----------------
// eo rows formed on the fly: eo[tok] = w0*y[r0] + w1*y[r1]
__global__ __launch_bounds__(256, 2)
void k_cross(const float* __restrict__ y, const float* __restrict__ x,
             const float* __restrict__ cw, const float* __restrict__ cb,
             const unsigned int* __restrict__ bmc,
             const int* __restrict__ t2row, const float* __restrict__ t2w,
             float* __restrict__ out)
{
  __shared__ ux4 Ash[2048];
  __shared__ __align__(16) ux2 Bsh[1024];

  const int NCT = 16;
  const int rt = blockIdx.x / NCT, ct = blockIdx.x % NCT;
  const int base = rt * BM;
  const int tid = threadIdx.x;
  const int jg0 = ct * 64;

  const int tok = base + tid;
  const int r0 = t2row[2 * tok], r1 = t2row[2 * tok + 1];
  const float w0 = t2w[2 * tok], w1 = t2w[2 * tok + 1];

  fx4 acc[4][4] = {};
  const int wave = tid >> 6, l = tid & 63;
  const int l16 = l & 15, lhi = l >> 4;

  unsigned int bits = bmc[ct];
  while (bits) {
    const int db = __ffs(bits) - 1; bits &= bits - 1;
    const int d0 = db * 64;
    {   // stage A: combine two pair rows -> bf16
      const fx4* s0 = (const fx4*)(y + (size_t)r0 * DIM + d0);
      const fx4* s1 = (const fx4*)(y + (size_t)r1 * DIM + d0);
      #pragma unroll
      for (int seg = 0; seg < 8; seg++) {
        fx4 p = w0 * s0[seg * 2]     + w1 * s1[seg * 2];
        fx4 q = w0 * s0[seg * 2 + 1] + w1 * s1[seg * 2 + 1];
        ux4 v;
        v[0] = f2bf(p[0]) | (f2bf(p[1]) << 16);
        v[1] = f2bf(p[2]) | (f2bf(p[3]) << 16);
        v[2] = f2bf(q[0]) | (f2bf(q[1]) << 16);
        v[3] = f2bf(q[2]) | (f2bf(q[3]) << 16);
        Ash[tid * 8 + (seg ^ (tid & 7))] = v;
      }
    }
    {   // stage B from cross_w
      const int kb = tid >> 4, jb = tid & 15;
      const float* bp = cw + (size_t)(d0 + kb * 4) * DIM + jg0 + jb * 4;
      fx4 r0v = *(const fx4*)bp;
      fx4 r1v = *(const fx4*)(bp + DIM);
      fx4 r2v = *(const fx4*)(bp + 2 * DIM);
      fx4 r3v = *(const fx4*)(bp + 3 * DIM);
      #pragma unroll
      for (int jj = 0; jj < 4; jj++) {
        ux2 val;
        val[0] = cvt_pk(r0v[jj], r1v[jj]);
        val[1] = cvt_pk(r2v[jj], r3v[jj]);
        const int col = jb * 4 + jj;
        Bsh[(col * 8 + ((kb >> 1) ^ (col & 7))) * 2 + (kb & 1)] = val;
      }
    }
    __syncthreads();
    #pragma unroll
    for (int ks = 0; ks < 2; ks++) {
      s8v a[4], b[4];
      const int seg = ks * 4 + lhi;
      #pragma unroll
      for (int m = 0; m < 4; m++) {
        const int row = wave * 64 + m * 16 + l16;
        V16 v; v.u = Ash[row * 8 + (seg ^ (row & 7))]; a[m] = v.s;
      }
      #pragma unroll
      for (int n = 0; n < 4; n++) {
        const int col = n * 16 + l16;
        V16 v; v.u = ((const ux4*)Bsh)[col * 8 + (seg ^ (col & 7))]; b[n] = v.s;
      }
      #pragma unroll
      for (int m = 0; m < 4; m++)
        #pragma unroll
        for (int n = 0; n < 4; n++)
          acc[m][n] = __builtin_amdgcn_mfma_f32_16x16x32_bf16(a[m], b[n], acc[m][n], 0, 0, 0);
    }
    __syncthreads();
  }

  #pragma unroll
  for (int m = 0; m < 4; m++)
    #pragma unroll
    for (int n = 0; n < 4; n++) {
      const int gcol = jg0 + n * 16 + l16;
      #pragma unroll
      for (int i = 0; i < 4; i++) {
        const int lrow = wave * 64 + m * 16 + lhi * 4 + i;
        const size_t idx = (size_t)(base + lrow) * DIM + gcol;
        out[idx] = acc[m][n][i] + x[idx] + cb[gcol];
      }
    }
}

// ---------------------------------------------------------------------------
extern "C" void kernel_launch(void* const* d_in, const int* in_sizes, int n_in,
                              void* d_out, int out_size, void* d_ws, size_t ws_size,
                              hipStream_t stream)
{
  (void)in_sizes; (void)n_in; (void)out_size;
  const float* x      = (const float*)d_in[0];
  const float* gate_w = (const float*)d_in[1];   // [2,16,1024]
  const float* temp   = (const float*)d_in[2];   // [2]
  const float* w1     = (const float*)d_in[3];   // [16,1024,4096]
  const float* b1     = (const float*)d_in[4];
  const float* w2     = (const float*)d_in[5];   // [16,4096,1024]
  const float* b2     = (const float*)d_in[6];
  const float* cw     = (const float*)d_in[7];   // [1024,1024]
  const float* cb     = (const float*)d_in[8];
  const void*  mask1  = d_in[9];
  const void*  mask2  = d_in[10];
  const void*  cmask  = d_in[11];
  float* out = (float*)d_out;
  char* ws = (char*)d_ws;

  size_t off = 0;
  auto walloc = [&](size_t b) { size_t r = off; off = (off + b + 255) & ~(size_t)255; return r; };
  size_t o_meta = walloc(4096);
  size_t o_bm1  = walloc(1024 * 4);
  size_t o_bm2  = walloc(256 * 8);
  size_t o_bmc  = walloc(64 * 4);
  size_t o_t2i  = walloc((size_t)NTOK * 2 * 4);
  size_t o_t2w  = walloc((size_t)NTOK * 2 * 4);
  size_t o_t2r  = walloc((size_t)NTOK * 2 * 4);
  size_t o_tok  = walloc((size_t)ROWS_CAP * 4);
  size_t o_xbf  = walloc((size_t)NTOK * DIM * 2);
  size_t o_y    = walloc((size_t)ROWS_CAP * DIM * 4);
  int HC = HID;
  while (HC > 256 && off + (size_t)ROWS_CAP * HC * 2 > ws_size) HC >>= 1;
  size_t o_hc   = walloc((size_t)ROWS_CAP * HC * 2);

  int*                meta = (int*)(ws + o_meta);
  unsigned int*       bm1  = (unsigned int*)(ws + o_bm1);
  unsigned long long* bm2  = (unsigned long long*)(ws + o_bm2);
  unsigned int*       bmc  = (unsigned int*)(ws + o_bmc);
  int*                t2i  = (int*)(ws + o_t2i);
  float*              t2w  = (float*)(ws + o_t2w);
  int*                t2r  = (int*)(ws + o_t2r);
  int*                tok  = (int*)(ws + o_tok);
  unsigned short*     xbf  = (unsigned short*)(ws + o_xbf);
  float*              y    = (float*)(ws + o_y);
  unsigned short*     hc   = (unsigned short*)(ws + o_hc);

  hipMemsetAsync(ws + o_meta, 0, 4096, stream);
  hipMemsetAsync(ws + o_tok, 0xFF, (size_t)ROWS_CAP * 4, stream);  // -1

  k_detect <<<64, 256, 0, stream>>>((const unsigned int*)mask1, meta);
  k_route  <<<NTOK / 4, 256, 0, stream>>>(x, gate_w + (size_t)1 * NEXP * DIM, temp + 1, t2i, t2w, meta);
  k_offsets<<<1, 64, 0, stream>>>(meta);
  k_assign <<<NTOK / 256, 256, 0, stream>>>(t2i, t2w, meta, tok, t2r);
  k_bmask  <<<4, 256, 0, stream>>>(mask1, mask2, cmask, meta, bm1, bm2, bmc);
  k_xcast  <<<(NTOK * DIM / 8) / 256, 256, 0, stream>>>(x, xbf);

  const int NRT = ROWS_CAP / BM;   // 80
  for (int c0 = 0; c0 < HID; c0 += HC) {
    k_gemm1<<<NRT * (HC / 64), 256, 0, stream>>>(xbf, w1, b1, bm1, meta, tok, hc, c0, HC);
    k_gemm2<<<NRT * 16, 256, 0, stream>>>(hc, w2, b2, bm2, meta, y, c0, HC);
  }
  k_cross<<<(NTOK / BM) * 16, 256, 0, stream>>>(y, x, cw, cb, bmc, t2r, t2w, out);
}